// Round 15
// baseline (520.074 us; speedup 1.0000x reference)
//
#include <hip/hip_runtime.h>

#define HD 64
#define NNODE 50000
#define NEDGE 100000
#define NGR 500
#define NPG 100      // nodes per graph (sorted, contiguous, equal size)
#define EPAD 100352  // 392 * 256
#define NCH 66       // packed B chunks of K=128 (0..63 data, 64 = bias rows, 65 zero)
#define NUPL 65      // u planes: 64 data + 1 bias(=1)

typedef _Float16 f16;
typedef _Float16 f16x2 __attribute__((ext_vector_type(2)));
typedef _Float16 f16x8 __attribute__((ext_vector_type(8)));
typedef float f32x4 __attribute__((ext_vector_type(4)));

__device__ __forceinline__ float sigmoidf_(float x) { return 1.f / (1.f + __expf(-x)); }

__device__ __forceinline__ void gload16(const void* g, void* l) {
    __builtin_amdgcn_global_load_lds((const __attribute__((address_space(1))) unsigned int*)g,
                                     (__attribute__((address_space(3))) unsigned int*)l, 16, 0, 0);
}

// ================= fused prep kernel (incl. pack_b) ==========
#define G_NODE 12500   // node_init: NNODE*64/256
#define G_EMLP 392     // edge_mlp: EPAD/256
#define G_PACK 66      // pack W2ext chunks
#define G_GRU  48      // prep_gru2
#define G_T1   128     // lwih transpose 256x128
#define G_T2   64      // lwhh transpose 256x64
#define G_IDX  392     // src/dst pad + degree count
#define G_ALL (G_NODE + G_EMLP + G_PACK + G_GRU + G_T1 + G_T2 + G_IDX)

__global__ __launch_bounds__(256) void k_prep_all(
    const float* __restrict__ nfeat, const float* __restrict__ lin0_w, const float* __restrict__ lin0_b,
    const float* __restrict__ efeat, const float* __restrict__ ew1, const float* __restrict__ eb1,
    const float* __restrict__ ew2, const float* __restrict__ eb2,
    const float* __restrict__ gwih, const float* __restrict__ gwhh,
    const float* __restrict__ lwih, const float* __restrict__ lwhh,
    const int* __restrict__ src, const int* __restrict__ dst,
    float* __restrict__ h, f16x2* __restrict__ uP, f16* __restrict__ w2hp,
    f16* __restrict__ gB1, f16* __restrict__ gB2,
    float* __restrict__ lwihT, float* __restrict__ lwhhT,
    int* __restrict__ srcP, int* __restrict__ dstP, int* __restrict__ cnt) {
    __shared__ float sw[5 * 128];
    __shared__ float sb[128];
    __shared__ float s[8192];
    int bb = blockIdx.x;
    int t = threadIdx.x;
    if (bb < G_NODE) {  // ---- node_init ----
        int idx = bb * 256 + t;
        int n = idx >> 6, o = idx & 63;
        if (n >= NNODE) return;
        const float* nf = nfeat + n * 32;
        float acc = lin0_b[o];
#pragma unroll
        for (int i = 0; i < 32; i++) acc += nf[i] * lin0_w[i * 64 + o];
        h[idx] = fmaxf(acc, 0.f);
        return;
    }
    bb -= G_NODE;
    if (bb < G_EMLP) {  // ---- edge_mlp: uP[c][e] = (u[2c], u[2c+1]); plane 64 = bias(=1) ----
        for (int idx = t; idx < 640; idx += 256) sw[idx] = ew1[idx];
        if (t < 128) sb[t] = eb1[t];
        __syncthreads();
        int e = bb * 256 + t;
        bool valid = e < NEDGE;
        float ef[5];
#pragma unroll
        for (int i = 0; i < 5; i++) ef[i] = valid ? efeat[e * 5 + i] : 0.f;
#pragma unroll 2
        for (int c = 0; c < 64; c++) {
            float v[2];
#pragma unroll
            for (int ss = 0; ss < 2; ss++) {
                int k = 2 * c + ss;
                float acc = sb[k];
#pragma unroll
                for (int i = 0; i < 5; i++) acc += ef[i] * sw[i * 128 + k];
                v[ss] = valid ? fmaxf(acc, 0.f) : 0.f;
            }
            f16x2 pv;
            pv[0] = (f16)v[0];
            pv[1] = (f16)v[1];
            uP[(size_t)c * EPAD + e] = pv;
        }
        {   // bias plane: u == 1 (0 for padding edges)
            f16x2 pv;
            pv[0] = valid ? (f16)1.f : (f16)0.f;
            pv[1] = pv[0];
            uP[(size_t)64 * EPAD + e] = pv;
        }
        return;
    }
    bb -= G_EMLP;
    if (bb < G_PACK) {  // ---- pack W2ext chunk bb into MFMA B-frag order (LDS tiled) ----
        int c = bb;
        for (int i = t; i < 8192; i += 256) {
            int kg = c * 128 + (i >> 6);
            float v = 0.f;
            if (kg < 8192) v = ew2[(size_t)c * 8192 + i];
            else if (kg < 8256) v = eb2[(kg - 8192) * 64 + (i & 63)];
            s[i] = v;
        }
        __syncthreads();
        f16* outp = w2hp + (size_t)c * 8192 + t * 32;
#pragma unroll
        for (int ff = 0; ff < 4; ff++) {
            int F = t * 4 + ff;          // F = sl*256 + jj*64 + l
            int l = F & 63;
            int jj = (F >> 6) & 3;
            int sl = (F >> 8) & 3;
            f16x8 v;
#pragma unroll
            for (int q = 0; q < 8; q++)
                v[q] = (f16)s[(sl * 32 + ((l >> 4) << 3) + q) * 64 + jj * 16 + (l & 15)];
            *(f16x8*)(outp + ff * 8) = v;
        }
        return;
    }
    bb -= G_PACK;
    if (bb < G_GRU) {  // ---- GRU weights -> f16, gate-col permuted ----
        int idx = bb * 256 + t;
        int cp = idx >> 6, k = idx & 63;
        int w = cp / 48, rem = cp % 48;
        int tg = rem >> 4, cc = rem & 15;
        int orow = tg * 64 + w * 16 + cc;
        gB1[idx] = (f16)gwih[orow * 64 + k];
        gB2[idx] = (f16)gwhh[orow * 64 + k];
        return;
    }
    bb -= G_GRU;
    if (bb < G_T1) {  // ---- lwih transpose ----
        int idx = bb * 256 + t;
        int r = idx >> 7, c = idx & 127;
        lwihT[c * 256 + r] = lwih[idx];
        return;
    }
    bb -= G_T1;
    if (bb < G_T2) {  // ---- lwhh transpose ----
        int idx = bb * 256 + t;
        int r = idx >> 6, c = idx & 63;
        lwhhT[c * 256 + r] = lwhh[idx];
        return;
    }
    bb -= G_T2;
    {  // ---- src/dst pad + degree count ----
        int e = bb * 256 + t;
        if (e >= EPAD) return;
        if (e < NEDGE) {
            int d = dst[e];
            srcP[e] = src[e];
            dstP[e] = d;
            atomicAdd(&cnt[d], 1);
        } else {
            srcP[e] = 0;
            dstP[e] = -1;
        }
    }
}

// ---------------- K6: msg GEMM + atomic scatter, N-split, 4-wave LDS-staged B ----------
// Block = 4 waves x 64 edges = 256 edges x ONE 32-col half (M_rep=4, N_rep=2, 16x16x32).
// Grid 784 -> 3136 waves = ~3 waves/SIMD (was 1.5): feeds the matrix pipe past the
// issue/dependency gaps that capped MfmaUtil at ~42%. B half-chunks (8KB) staged via
// global_load_lds, 2-chunk periods, double-buffered (32KB LDS).
__global__ __launch_bounds__(256) void k_msg(
    const float* __restrict__ h, const f16x2* __restrict__ uP, const f16* __restrict__ w2hp,
    const int* __restrict__ srcP, const int* __restrict__ dstP, float* __restrict__ agg) {
    __shared__ __attribute__((aligned(16))) f16 sB[2 * 8192];  // 2 bufs x 16KB (2 half-chunks)
    int t = threadIdx.x;
    int w = t >> 6, l = t & 63;
    int bid = blockIdx.x;
    int ch = bid & 1;                        // column half
    int eb = (bid >> 1) * 256 + w * 64;      // per-wave edge base
    int lr = l & 15, lg = l >> 4;
    // A-side x fragments: xf[i][p][q] = f16(h[src[eb+i*16+lr]][p*32 + lg*8 + q])
    f16x8 xf[4][2];
#pragma unroll
    for (int i = 0; i < 4; i++) {
        const float* xb = h + (size_t)srcP[eb + i * 16 + lr] * 64;
#pragma unroll
        for (int p = 0; p < 2; p++) {
            float4 v0 = *(const float4*)(xb + p * 32 + lg * 8);
            float4 v1 = *(const float4*)(xb + p * 32 + lg * 8 + 4);
            f16x8 xv;
            xv[0] = (f16)v0.x; xv[1] = (f16)v0.y; xv[2] = (f16)v0.z; xv[3] = (f16)v0.w;
            xv[4] = (f16)v1.x; xv[5] = (f16)v1.y; xv[6] = (f16)v1.z; xv[7] = (f16)v1.w;
            xf[i][p] = xv;
        }
    }
    const f16x8* gB = (const f16x8*)w2hp;
    f16x8* sB8 = (f16x8*)sB;
    // staging map: LDS slot s2 = q*512 + sl*128 + jj2*64 + lane covers global frag
    //   F = chunk*1024 + sl*256 + (2*ch + jj2)*64 + lane   (q = chunk within period)
    // thread t covers s2 in {t, t+256} per chunk; wave-uniform base + lane*16 holds.
#define STAGE_PAIR(PAIR, LDSBASE)                                                       \
    {                                                                                   \
        _Pragma("unroll") for (int q = 0; q < 2; q++) {                                 \
            size_t cbase = ((size_t)(PAIR) * 2 + q) * 1024;                             \
            _Pragma("unroll") for (int i2 = 0; i2 < 2; i2++) {                          \
                int s2 = t + 256 * i2;                                                  \
                int sl = s2 >> 7, jj2 = (s2 >> 6) & 1;                                  \
                gload16(gB + cbase + sl * 256 + (2 * ch + jj2) * 64 + (s2 & 63),        \
                        sB8 + (LDSBASE) + q * 512 + s2);                                \
            }                                                                           \
        }                                                                               \
    }
    STAGE_PAIR(0, 0)
    f32x4 acc[4][2];
#pragma unroll
    for (int i = 0; i < 4; i++) {
        acc[i][0] = (f32x4){0.f, 0.f, 0.f, 0.f};
        acc[i][1] = (f32x4){0.f, 0.f, 0.f, 0.f};
    }
    f16x2 uc0[4], uc1[4], un0[4], un1[4];
#pragma unroll
    for (int i = 0; i < 4; i++) {
        uc0[i] = uP[eb + i * 16 + lr];                  // plane 0
        uc1[i] = uP[(size_t)EPAD + eb + i * 16 + lr];   // plane 1
    }
    __syncthreads();  // drains vmcnt: buf0 ready
#pragma unroll 1
    for (int p = 0; p <= 32; p++) {
        int buf = p & 1;
        if (p < 32) {  // stage next pair into other buffer + prefetch u planes
            STAGE_PAIR(p + 1, (buf ^ 1) * 1024)
            int c0 = min(2 * p + 2, 64), c1 = min(2 * p + 3, 64);
#pragma unroll
            for (int i = 0; i < 4; i++) {
                un0[i] = uP[(size_t)c0 * EPAD + eb + i * 16 + lr];
                un1[i] = uP[(size_t)c1 * EPAD + eb + i * 16 + lr];
            }
        }
#pragma unroll
        for (int q = 0; q < 2; q++) {
            f16x8 bf[4][2];
#pragma unroll
            for (int s = 0; s < 4; s++)
#pragma unroll
                for (int j = 0; j < 2; j++)
                    bf[s][j] = sB8[buf * 1024 + q * 512 + s * 128 + j * 64 + l];
            __builtin_amdgcn_s_setprio(1);
#pragma unroll
            for (int s = 0; s < 4; s++)
#pragma unroll
                for (int i = 0; i < 4; i++) {
                    f16 uu = (q == 0) ? uc0[i][s >> 1] : uc1[i][s >> 1];
                    f16x8 av = xf[i][s & 1] * uu;
                    acc[i][0] = __builtin_amdgcn_mfma_f32_16x16x32_f16(av, bf[s][0], acc[i][0], 0, 0, 0);
                    acc[i][1] = __builtin_amdgcn_mfma_f32_16x16x32_f16(av, bf[s][1], acc[i][1], 0, 0, 0);
                }
            __builtin_amdgcn_s_setprio(0);
        }
#pragma unroll
        for (int i = 0; i < 4; i++) { uc0[i] = un0[i]; uc1[i] = un1[i]; }
        __syncthreads();  // all reads of buf done; staged buf^1 landed (vmcnt drained)
    }
    // atomic scatter: C layout col = ch*32 + j*16 + lr, row = (lane>>4)*4+reg
#pragma unroll
    for (int i = 0; i < 4; i++) {
        int rb = eb + i * 16 + lg * 4;
        int4 d4 = *(const int4*)(dstP + rb);
#pragma unroll
        for (int r = 0; r < 4; r++) {
            int d = (r == 0) ? d4.x : (r == 1) ? d4.y : (r == 2) ? d4.z : d4.w;
            if (d >= 0) {
                float* ap = agg + (size_t)d * 64 + ch * 32 + lr;
                atomicAdd(ap, acc[i][0][r]);
                atomicAdd(ap + 16, acc[i][1][r]);
            }
        }
    }
}

// ---------------- K7: GRU via MFMA, 64 nodes/block; optionally zeroes agg --------
#define GWP 72
__global__ __launch_bounds__(256) void k_gru2(float* __restrict__ agg,
                                              const int* __restrict__ cnt,
                                              const float* __restrict__ convb,
                                              const f16* __restrict__ B1g,
                                              const f16* __restrict__ B2g,
                                              const float* __restrict__ bih,
                                              const float* __restrict__ bhh,
                                              float* __restrict__ h, int zero_agg) {
    __shared__ f16 sM[64 * GWP];
    __shared__ f16 sH[64 * GWP];
    int t = threadIdx.x;
    int nb = blockIdx.x * 64;
    int w = t >> 6, l = t & 63, lr = l & 15, lg = l >> 4;
    f16x8 b1[2][3], b2[2][3];
#pragma unroll
    for (int kk = 0; kk < 2; kk++)
#pragma unroll
        for (int j = 0; j < 3; j++) {
            size_t off = (size_t)(w * 48 + j * 16 + lr) * 64 + kk * 32 + lg * 8;
            b1[kk][j] = *(const f16x8*)(B1g + off);
            b2[kk][j] = *(const f16x8*)(B2g + off);
        }
#pragma unroll
    for (int it = 0; it < 16; it++) {
        int idx = t + 256 * it;
        int node = idx >> 6, k = idx & 63;
        int gn = nb + node;
        float mv = 0.f, hv = 0.f;
        if (gn < NNODE) {
            size_t off = (size_t)gn * 64 + k;
            float dinv = 1.f / (float)max(cnt[gn], 1);
            mv = fmaxf(agg[off] * dinv + convb[k], 0.f);
            hv = h[off];
            if (zero_agg) agg[off] = 0.f;  // reset for next msg pass
        }
        sM[node * GWP + k] = (f16)mv;
        sH[node * GWP + k] = (f16)hv;
    }
    __syncthreads();
    f32x4 aih[4][3], ahh[4][3];
#pragma unroll
    for (int i = 0; i < 4; i++)
#pragma unroll
        for (int j = 0; j < 3; j++) {
            aih[i][j] = (f32x4){0.f, 0.f, 0.f, 0.f};
            ahh[i][j] = (f32x4){0.f, 0.f, 0.f, 0.f};
        }
#pragma unroll
    for (int kk = 0; kk < 2; kk++) {
        f16x8 am[4], ah[4];
#pragma unroll
        for (int i = 0; i < 4; i++) {
            am[i] = *(const f16x8*)(sM + (i * 16 + lr) * GWP + kk * 32 + lg * 8);
            ah[i] = *(const f16x8*)(sH + (i * 16 + lr) * GWP + kk * 32 + lg * 8);
        }
#pragma unroll
        for (int i = 0; i < 4; i++)
#pragma unroll
            for (int j = 0; j < 3; j++) {
                aih[i][j] = __builtin_amdgcn_mfma_f32_16x16x32_f16(am[i], b1[kk][j], aih[i][j], 0, 0, 0);
                ahh[i][j] = __builtin_amdgcn_mfma_f32_16x16x32_f16(ah[i], b2[kk][j], ahh[i][j], 0, 0, 0);
            }
    }
    float bi0 = bih[0 * 64 + w * 16 + lr], bh0 = bhh[0 * 64 + w * 16 + lr];
    float bi1 = bih[1 * 64 + w * 16 + lr], bh1 = bhh[1 * 64 + w * 16 + lr];
    float bi2 = bih[2 * 64 + w * 16 + lr], bh2 = bhh[2 * 64 + w * 16 + lr];
#pragma unroll
    for (int i = 0; i < 4; i++)
#pragma unroll
        for (int r = 0; r < 4; r++) {
            int node = i * 16 + lg * 4 + r;
            int gn = nb + node;
            if (gn >= NNODE) continue;
            float rg = sigmoidf_(aih[i][0][r] + bi0 + ahh[i][0][r] + bh0);
            float z = sigmoidf_(aih[i][1][r] + bi1 + ahh[i][1][r] + bh1);
            float nn = tanhf(aih[i][2][r] + bi2 + rg * (ahh[i][2][r] + bh2));
            size_t off = (size_t)gn * 64 + w * 16 + lr;
            float hold = h[off];
            h[off] = (1.f - z) * nn + z * hold;
        }
}

// ---------------- K8: fused Set2Set (3x LSTM + attention) + final MLP, block per graph ----
#define FP 68
__global__ __launch_bounds__(256) void k_s2s(const float* __restrict__ feat,
                                             const float* __restrict__ wihT,
                                             const float* __restrict__ whhT,
                                             const float* __restrict__ lbih,
                                             const float* __restrict__ lbhh,
                                             const float* __restrict__ fc1w,
                                             const float* __restrict__ fc1b,
                                             const float* __restrict__ fc2w,
                                             const float* __restrict__ fc2b,
                                             float* __restrict__ out) {
    __shared__ float sf[NPG * FP];
    __shared__ float sq[128];
    __shared__ float sh[64], scc[64];
    __shared__ float sg[256];
    __shared__ float se[NPG];
    __shared__ float red[2];
    int g = blockIdx.x, t = threadIdx.x;
    const float* fb = feat + (size_t)g * NPG * 64;
    for (int idx = t; idx < NPG * 64; idx += 256)
        sf[(idx >> 6) * FP + (idx & 63)] = fb[idx];
    if (t < 128) sq[t] = 0.f;
    if (t >= 128 && t < 192) { sh[t - 128] = 0.f; scc[t - 128] = 0.f; }
    __syncthreads();
    for (int it = 0; it < 3; it++) {
        float gate = lbih[t] + lbhh[t];
#pragma unroll 8
        for (int i = 0; i < 128; i++) gate += sq[i] * wihT[i * 256 + t];
#pragma unroll 8
        for (int i = 0; i < 64; i++) gate += sh[i] * whhT[i * 256 + t];
        sg[t] = gate;
        __syncthreads();
        if (t < 64) {
            float ig = sigmoidf_(sg[t]);
            float fg = sigmoidf_(sg[64 + t]);
            float gg = tanhf(sg[128 + t]);
            float og = sigmoidf_(sg[192 + t]);
            float c = fg * scc[t] + ig * gg;
            scc[t] = c;
            float hv = og * tanhf(c);
            sh[t] = hv;
            sq[t] = hv;
        }
        __syncthreads();
        if (t < NPG) {
            float e = 0.f;
#pragma unroll 8
            for (int o = 0; o < 64; o++) e += sf[t * FP + o] * sh[o];
            se[t] = e;
        }
        __syncthreads();
        if (t < 64) {
            float m = -1e30f;
            for (int i2 = t; i2 < NPG; i2 += 64) m = fmaxf(m, se[i2]);
            for (int d = 32; d; d >>= 1) m = fmaxf(m, __shfl_down(m, d));
            if (t == 0) red[0] = m;
        }
        __syncthreads();
        float emax = red[0];
        if (t < NPG) se[t] = __expf(se[t] - emax);
        __syncthreads();
        if (t < 64) {
            float s = 0.f;
            for (int i2 = t; i2 < NPG; i2 += 64) s += se[i2];
            for (int d = 32; d; d >>= 1) s += __shfl_down(s, d);
            if (t == 0) red[1] = s;
        }
        __syncthreads();
        if (t < 64) {
            float dnv = 1.f / red[1];
            float r = 0.f;
#pragma unroll 4
            for (int n = 0; n < NPG; n++) r += se[n] * sf[n * FP + t];
            sq[64 + t] = r * dnv;
        }
        __syncthreads();
    }
    if (t < 64) {
        float hsum = fc1b[t];
#pragma unroll 8
        for (int i = 0; i < 128; i++) hsum += sq[i] * fc1w[i * 64 + t];
        float p = fmaxf(hsum, 0.f) * fc2w[t];
        for (int d = 32; d; d >>= 1) p += __shfl_down(p, d);
        if (t == 0) out[g] = p + fc2b[0];
    }
}

extern "C" void kernel_launch(void* const* d_in, const int* in_sizes, int n_in,
                              void* d_out, int out_size, void* d_ws, size_t ws_size,
                              hipStream_t stream) {
    const float* nfeat = (const float*)d_in[0];
    const float* efeat = (const float*)d_in[1];
    const float* lin0_w = (const float*)d_in[2];
    const float* lin0_b = (const float*)d_in[3];
    const float* ew1 = (const float*)d_in[4];
    const float* eb1 = (const float*)d_in[5];
    const float* ew2 = (const float*)d_in[6];
    const float* eb2 = (const float*)d_in[7];
    const float* convb = (const float*)d_in[8];
    const float* gwih = (const float*)d_in[9];
    const float* gwhh = (const float*)d_in[10];
    const float* gbih = (const float*)d_in[11];
    const float* gbhh = (const float*)d_in[12];
    const float* lwih = (const float*)d_in[13];
    const float* lwhh = (const float*)d_in[14];
    const float* lbih = (const float*)d_in[15];
    const float* lbhh = (const float*)d_in[16];
    const float* fc1w = (const float*)d_in[17];
    const float* fc1b = (const float*)d_in[18];
    const float* fc2w = (const float*)d_in[19];
    const float* fc2b = (const float*)d_in[20];
    const int* src = (const int*)d_in[21];
    const int* dst = (const int*)d_in[22];
    float* out = (float*)d_out;

    char* p = (char*)d_ws;
    auto alloc = [&](size_t bytes) {
        char* q = p;
        p += (bytes + 255) & ~(size_t)255;
        return q;
    };
    f16x2* uP = (f16x2*)alloc((size_t)NUPL * EPAD * 4);     // 26.1 MB
    f16* w2hp = (f16*)alloc((size_t)NCH * 8192 * 2);        // 1.08 MB
    float* h = (float*)alloc((size_t)NNODE * 64 * 4);       // 12.8 MB
    float* agg = (float*)alloc((size_t)NNODE * 64 * 4);     // 12.8 MB
    int* cnt = (int*)alloc((size_t)NNODE * 4);
    float* lwihT = (float*)alloc((size_t)128 * 256 * 4);
    float* lwhhT = (float*)alloc((size_t)64 * 256 * 4);
    f16* gB1 = (f16*)alloc((size_t)12288 * 2);
    f16* gB2 = (f16*)alloc((size_t)12288 * 2);
    int* srcP = (int*)alloc((size_t)EPAD * 4);
    int* dstP = (int*)alloc((size_t)EPAD * 4);
    if ((size_t)(p - (char*)d_ws) > ws_size) return;  // ~55 MB total

    hipMemsetAsync(cnt, 0, (size_t)NNODE * 4, stream);
    hipMemsetAsync(agg, 0, (size_t)NNODE * 64 * 4, stream);  // once; k_gru2 re-zeroes

    k_prep_all<<<G_ALL, 256, 0, stream>>>(nfeat, lin0_w, lin0_b, efeat, ew1, eb1, ew2, eb2,
                                          gwih, gwhh, lwih, lwhh, src, dst,
                                          h, uP, w2hp, gB1, gB2, lwihT, lwhhT, srcP, dstP, cnt);

    for (int it = 0; it < 3; it++) {
        k_msg<<<(EPAD / 256) * 2, 256, 0, stream>>>(h, uP, w2hp, srcP, dstP, agg);
        k_gru2<<<(NNODE + 63) / 64, 256, 0, stream>>>(agg, cnt, convb, gB1, gB2, gbih, gbhh, h,
                                                      it < 2 ? 1 : 0);
    }
    k_s2s<<<NGR, 256, 0, stream>>>(h, lwihT, lwhhT, lbih, lbhh, fc1w, fc1b, fc2w, fc2b, out);
}

// Round 16
// 504.658 us; speedup vs baseline: 1.0305x; 1.0305x over previous
//
#include <hip/hip_runtime.h>

#define HD 64
#define NNODE 50000
#define NEDGE 100000
#define NGR 500
#define NPG 100      // nodes per graph (sorted, contiguous, equal size)
#define EPAD 100352  // 392 * 256
#define NCH 66       // packed B chunks of K=128 (0..63 data, 64 = bias rows, 65 zero)
#define NUPL 65      // u planes: 64 data + 1 bias(=1)

typedef _Float16 f16;
typedef _Float16 f16x2 __attribute__((ext_vector_type(2)));
typedef _Float16 f16x8 __attribute__((ext_vector_type(8)));
typedef float f32x4 __attribute__((ext_vector_type(4)));
typedef float f32x16 __attribute__((ext_vector_type(16)));

__device__ __forceinline__ float sigmoidf_(float x) { return 1.f / (1.f + __expf(-x)); }

__device__ __forceinline__ void gload16(const void* g, void* l) {
    __builtin_amdgcn_global_load_lds((const __attribute__((address_space(1))) unsigned int*)g,
                                     (__attribute__((address_space(3))) unsigned int*)l, 16, 0, 0);
}

// ================= fused prep kernel (incl. pack_b, 32x32 frag order) ==========
#define G_NODE 12500   // node_init: NNODE*64/256
#define G_EMLP 392     // edge_mlp: EPAD/256
#define G_PACK 66      // pack W2ext chunks
#define G_GRU  48      // prep_gru2
#define G_T1   128     // lwih transpose 256x128
#define G_T2   64      // lwhh transpose 256x64
#define G_IDX  392     // src/dst pad + degree count
#define G_ALL (G_NODE + G_EMLP + G_PACK + G_GRU + G_T1 + G_T2 + G_IDX)

__global__ __launch_bounds__(256) void k_prep_all(
    const float* __restrict__ nfeat, const float* __restrict__ lin0_w, const float* __restrict__ lin0_b,
    const float* __restrict__ efeat, const float* __restrict__ ew1, const float* __restrict__ eb1,
    const float* __restrict__ ew2, const float* __restrict__ eb2,
    const float* __restrict__ gwih, const float* __restrict__ gwhh,
    const float* __restrict__ lwih, const float* __restrict__ lwhh,
    const int* __restrict__ src, const int* __restrict__ dst,
    float* __restrict__ h, f16x2* __restrict__ uP, f16* __restrict__ w2hp,
    f16* __restrict__ gB1, f16* __restrict__ gB2,
    float* __restrict__ lwihT, float* __restrict__ lwhhT,
    int* __restrict__ srcP, int* __restrict__ dstP, int* __restrict__ cnt) {
    __shared__ float sw[5 * 128];
    __shared__ float sb[128];
    __shared__ float s[8192];
    int bb = blockIdx.x;
    int t = threadIdx.x;
    if (bb < G_NODE) {  // ---- node_init ----
        int idx = bb * 256 + t;
        int n = idx >> 6, o = idx & 63;
        if (n >= NNODE) return;
        const float* nf = nfeat + n * 32;
        float acc = lin0_b[o];
#pragma unroll
        for (int i = 0; i < 32; i++) acc += nf[i] * lin0_w[i * 64 + o];
        h[idx] = fmaxf(acc, 0.f);
        return;
    }
    bb -= G_NODE;
    if (bb < G_EMLP) {  // ---- edge_mlp: uP[c][e] = (u[2c], u[2c+1]); plane 64 = bias(=1) ----
        for (int idx = t; idx < 640; idx += 256) sw[idx] = ew1[idx];
        if (t < 128) sb[t] = eb1[t];
        __syncthreads();
        int e = bb * 256 + t;
        bool valid = e < NEDGE;
        float ef[5];
#pragma unroll
        for (int i = 0; i < 5; i++) ef[i] = valid ? efeat[e * 5 + i] : 0.f;
#pragma unroll 2
        for (int c = 0; c < 64; c++) {
            float v[2];
#pragma unroll
            for (int ss = 0; ss < 2; ss++) {
                int k = 2 * c + ss;
                float acc = sb[k];
#pragma unroll
                for (int i = 0; i < 5; i++) acc += ef[i] * sw[i * 128 + k];
                v[ss] = valid ? fmaxf(acc, 0.f) : 0.f;
            }
            f16x2 pv;
            pv[0] = (f16)v[0];
            pv[1] = (f16)v[1];
            uP[(size_t)c * EPAD + e] = pv;
        }
        {   // bias plane: u == 1 (0 for padding edges)
            f16x2 pv;
            pv[0] = valid ? (f16)1.f : (f16)0.f;
            pv[1] = pv[0];
            uP[(size_t)64 * EPAD + e] = pv;
        }
        return;
    }
    bb -= G_EMLP;
    if (bb < G_PACK) {  // ---- pack W2ext chunk into 32x32x16 B-frag order (LDS tiled) ----
        // f16x8 index F = c*1024 + s*128 + j*64 + l
        // value[q] = W2ext[c*128 + s*16 + (l>>5)*8 + q][j*32 + (l&31)]
        int c = bb;
        for (int i = t; i < 8192; i += 256) {
            int kg = c * 128 + (i >> 6);
            float v = 0.f;
            if (kg < 8192) v = ew2[(size_t)c * 8192 + i];
            else if (kg < 8256) v = eb2[(kg - 8192) * 64 + (i & 63)];
            s[i] = v;
        }
        __syncthreads();
        f16* outp = w2hp + (size_t)c * 8192 + t * 32;
#pragma unroll
        for (int ff = 0; ff < 4; ff++) {
            int F = t * 4 + ff;          // F = sl*128 + j*64 + l
            int l = F & 63;
            int jj = (F >> 6) & 1;
            int sl = F >> 7;
            f16x8 v;
#pragma unroll
            for (int q = 0; q < 8; q++)
                v[q] = (f16)s[(sl * 16 + ((l >> 5) << 3) + q) * 64 + jj * 32 + (l & 31)];
            *(f16x8*)(outp + ff * 8) = v;
        }
        return;
    }
    bb -= G_PACK;
    if (bb < G_GRU) {  // ---- GRU weights -> f16, gate-col permuted ----
        int idx = bb * 256 + t;
        int cp = idx >> 6, k = idx & 63;
        int w = cp / 48, rem = cp % 48;
        int tg = rem >> 4, cc = rem & 15;
        int orow = tg * 64 + w * 16 + cc;
        gB1[idx] = (f16)gwih[orow * 64 + k];
        gB2[idx] = (f16)gwhh[orow * 64 + k];
        return;
    }
    bb -= G_GRU;
    if (bb < G_T1) {  // ---- lwih transpose ----
        int idx = bb * 256 + t;
        int r = idx >> 7, c = idx & 127;
        lwihT[c * 256 + r] = lwih[idx];
        return;
    }
    bb -= G_T1;
    if (bb < G_T2) {  // ---- lwhh transpose ----
        int idx = bb * 256 + t;
        int r = idx >> 6, c = idx & 63;
        lwhhT[c * 256 + r] = lwhh[idx];
        return;
    }
    bb -= G_T2;
    {  // ---- src/dst pad + degree count ----
        int e = bb * 256 + t;
        if (e >= EPAD) return;
        if (e < NEDGE) {
            int d = dst[e];
            srcP[e] = src[e];
            dstP[e] = d;
            atomicAdd(&cnt[d], 1);
        } else {
            srcP[e] = 0;
            dstP[e] = -1;
        }
    }
}

// ---------------- K6: msg GEMM + atomic scatter, 32x32x16 MFMA, 4-wave LDS-staged B -------
// Block = 4 waves x 64 edges = 256 edges, 64 cols. Wave tiles: M 2x32, N 2x32 (32 MFMA/chunk,
// half of R14's 64 -> halves per-wave MFMA instruction-blocking; 2x FLOP per instruction).
// TWO chunks (32KB) per barrier period, double-buffered (64KB LDS).
__global__ __launch_bounds__(256) void k_msg(
    const float* __restrict__ h, const f16x2* __restrict__ uP, const f16* __restrict__ w2hp,
    const int* __restrict__ srcP, const int* __restrict__ dstP, float* __restrict__ agg) {
    __shared__ __attribute__((aligned(16))) f16 sB[2 * 16384];  // 2 bufs x 32KB (2 chunks)
    int t = threadIdx.x;
    int w = t >> 6, l = t & 63;
    int eb = blockIdx.x * 256 + w * 64;  // per-wave edge base
    int lm = l & 31, hi = l >> 5;
    // A-side x fragments: xf[i][h4][q] = f16(h[src[eb+i*32+lm]][h4*16 + hi*8 + q])
    f16x8 xf[2][4];
#pragma unroll
    for (int i = 0; i < 2; i++) {
        const float* xb = h + (size_t)srcP[eb + i * 32 + lm] * 64;
#pragma unroll
        for (int h4 = 0; h4 < 4; h4++) {
            float4 v0 = *(const float4*)(xb + h4 * 16 + hi * 8);
            float4 v1 = *(const float4*)(xb + h4 * 16 + hi * 8 + 4);
            f16x8 xv;
            xv[0] = (f16)v0.x; xv[1] = (f16)v0.y; xv[2] = (f16)v0.z; xv[3] = (f16)v0.w;
            xv[4] = (f16)v1.x; xv[5] = (f16)v1.y; xv[6] = (f16)v1.z; xv[7] = (f16)v1.w;
            xf[i][h4] = xv;
        }
    }
    const f16x8* gB = (const f16x8*)w2hp;
    f16x8* sB8 = (f16x8*)sB;
    // stage pair 0 (chunks 0,1) into buf 0: 8 f16x8 slots per thread (linear copy)
#pragma unroll
    for (int i = 0; i < 8; i++)
        gload16(gB + i * 256 + t, sB8 + i * 256 + t);
    f32x16 acc00, acc01, acc10, acc11;
#pragma unroll
    for (int r = 0; r < 16; r++) { acc00[r] = 0.f; acc01[r] = 0.f; acc10[r] = 0.f; acc11[r] = 0.f; }
    f16x2 uc0[2], uc1[2], un0[2], un1[2];
#pragma unroll
    for (int i = 0; i < 2; i++) {
        uc0[i] = uP[eb + i * 32 + lm];                  // plane 0
        uc1[i] = uP[(size_t)EPAD + eb + i * 32 + lm];   // plane 1
    }
    __syncthreads();  // drains vmcnt: buf0 ready
#pragma unroll 1
    for (int p = 0; p <= 32; p++) {
        int buf = p & 1;
        if (p < 32) {  // stage next pair into other buffer + prefetch u planes
            const f16x8* gs = gB + (size_t)(p + 1) * 2048;
            f16x8* ld = sB8 + (buf ^ 1) * 2048;
#pragma unroll
            for (int i = 0; i < 8; i++)
                gload16(gs + i * 256 + t, ld + i * 256 + t);
            int c0 = min(2 * p + 2, 64), c1 = min(2 * p + 3, 64);
#pragma unroll
            for (int i = 0; i < 2; i++) {
                un0[i] = uP[(size_t)c0 * EPAD + eb + i * 32 + lm];
                un1[i] = uP[(size_t)c1 * EPAD + eb + i * 32 + lm];
            }
        }
#pragma unroll
        for (int q = 0; q < 2; q++) {
            __builtin_amdgcn_s_setprio(1);
#pragma unroll
            for (int s = 0; s < 8; s++) {
                f16x8 bf0 = sB8[buf * 2048 + q * 1024 + s * 128 + l];
                f16x8 bf1 = sB8[buf * 2048 + q * 1024 + s * 128 + 64 + l];
                f16 u0 = (q == 0) ? uc0[0][s >> 2] : uc1[0][s >> 2];
                f16 u1 = (q == 0) ? uc0[1][s >> 2] : uc1[1][s >> 2];
                f16x8 av0 = xf[0][s & 3] * u0;
                f16x8 av1 = xf[1][s & 3] * u1;
                acc00 = __builtin_amdgcn_mfma_f32_32x32x16_f16(av0, bf0, acc00, 0, 0, 0);
                acc01 = __builtin_amdgcn_mfma_f32_32x32x16_f16(av0, bf1, acc01, 0, 0, 0);
                acc10 = __builtin_amdgcn_mfma_f32_32x32x16_f16(av1, bf0, acc10, 0, 0, 0);
                acc11 = __builtin_amdgcn_mfma_f32_32x32x16_f16(av1, bf1, acc11, 0, 0, 0);
            }
            __builtin_amdgcn_s_setprio(0);
        }
#pragma unroll
        for (int i = 0; i < 2; i++) { uc0[i] = un0[i]; uc1[i] = un1[i]; }
        __syncthreads();  // all reads of buf done; staged buf^1 landed (vmcnt drained)
    }
    // atomic scatter: C layout col = lane&31, row = (reg&3) + 8*(reg>>2) + 4*(lane>>5)
#pragma unroll
    for (int i = 0; i < 2; i++) {
#pragma unroll
        for (int b = 0; b < 4; b++) {
            int4 d4 = *(const int4*)(dstP + eb + i * 32 + 8 * b + 4 * hi);
#pragma unroll
            for (int rr = 0; rr < 4; rr++) {
                int d = (rr == 0) ? d4.x : (rr == 1) ? d4.y : (rr == 2) ? d4.z : d4.w;
                if (d >= 0) {
                    float v0 = (i == 0) ? acc00[b * 4 + rr] : acc10[b * 4 + rr];
                    float v1 = (i == 0) ? acc01[b * 4 + rr] : acc11[b * 4 + rr];
                    float* ap = agg + (size_t)d * 64 + lm;
                    atomicAdd(ap, v0);
                    atomicAdd(ap + 32, v1);
                }
            }
        }
    }
}

// ---------------- K7: GRU via MFMA, 64 nodes/block; optionally zeroes agg --------
#define GWP 72
__global__ __launch_bounds__(256) void k_gru2(float* __restrict__ agg,
                                              const int* __restrict__ cnt,
                                              const float* __restrict__ convb,
                                              const f16* __restrict__ B1g,
                                              const f16* __restrict__ B2g,
                                              const float* __restrict__ bih,
                                              const float* __restrict__ bhh,
                                              float* __restrict__ h, int zero_agg) {
    __shared__ f16 sM[64 * GWP];
    __shared__ f16 sH[64 * GWP];
    int t = threadIdx.x;
    int nb = blockIdx.x * 64;
    int w = t >> 6, l = t & 63, lr = l & 15, lg = l >> 4;
    f16x8 b1[2][3], b2[2][3];
#pragma unroll
    for (int kk = 0; kk < 2; kk++)
#pragma unroll
        for (int j = 0; j < 3; j++) {
            size_t off = (size_t)(w * 48 + j * 16 + lr) * 64 + kk * 32 + lg * 8;
            b1[kk][j] = *(const f16x8*)(B1g + off);
            b2[kk][j] = *(const f16x8*)(B2g + off);
        }
#pragma unroll
    for (int it = 0; it < 16; it++) {
        int idx = t + 256 * it;
        int node = idx >> 6, k = idx & 63;
        int gn = nb + node;
        float mv = 0.f, hv = 0.f;
        if (gn < NNODE) {
            size_t off = (size_t)gn * 64 + k;
            float dinv = 1.f / (float)max(cnt[gn], 1);
            mv = fmaxf(agg[off] * dinv + convb[k], 0.f);
            hv = h[off];
            if (zero_agg) agg[off] = 0.f;  // reset for next msg pass
        }
        sM[node * GWP + k] = (f16)mv;
        sH[node * GWP + k] = (f16)hv;
    }
    __syncthreads();
    f32x4 aih[4][3], ahh[4][3];
#pragma unroll
    for (int i = 0; i < 4; i++)
#pragma unroll
        for (int j = 0; j < 3; j++) {
            aih[i][j] = (f32x4){0.f, 0.f, 0.f, 0.f};
            ahh[i][j] = (f32x4){0.f, 0.f, 0.f, 0.f};
        }
#pragma unroll
    for (int kk = 0; kk < 2; kk++) {
        f16x8 am[4], ah[4];
#pragma unroll
        for (int i = 0; i < 4; i++) {
            am[i] = *(const f16x8*)(sM + (i * 16 + lr) * GWP + kk * 32 + lg * 8);
            ah[i] = *(const f16x8*)(sH + (i * 16 + lr) * GWP + kk * 32 + lg * 8);
        }
#pragma unroll
        for (int i = 0; i < 4; i++)
#pragma unroll
            for (int j = 0; j < 3; j++) {
                aih[i][j] = __builtin_amdgcn_mfma_f32_16x16x32_f16(am[i], b1[kk][j], aih[i][j], 0, 0, 0);
                ahh[i][j] = __builtin_amdgcn_mfma_f32_16x16x32_f16(ah[i], b2[kk][j], ahh[i][j], 0, 0, 0);
            }
    }
    float bi0 = bih[0 * 64 + w * 16 + lr], bh0 = bhh[0 * 64 + w * 16 + lr];
    float bi1 = bih[1 * 64 + w * 16 + lr], bh1 = bhh[1 * 64 + w * 16 + lr];
    float bi2 = bih[2 * 64 + w * 16 + lr], bh2 = bhh[2 * 64 + w * 16 + lr];
#pragma unroll
    for (int i = 0; i < 4; i++)
#pragma unroll
        for (int r = 0; r < 4; r++) {
            int node = i * 16 + lg * 4 + r;
            int gn = nb + node;
            if (gn >= NNODE) continue;
            float rg = sigmoidf_(aih[i][0][r] + bi0 + ahh[i][0][r] + bh0);
            float z = sigmoidf_(aih[i][1][r] + bi1 + ahh[i][1][r] + bh1);
            float nn = tanhf(aih[i][2][r] + bi2 + rg * (ahh[i][2][r] + bh2));
            size_t off = (size_t)gn * 64 + w * 16 + lr;
            float hold = h[off];
            h[off] = (1.f - z) * nn + z * hold;
        }
}

// ---------------- K8: fused Set2Set (3x LSTM + attention) + final MLP, block per graph ----
#define FP 68
__global__ __launch_bounds__(256) void k_s2s(const float* __restrict__ feat,
                                             const float* __restrict__ wihT,
                                             const float* __restrict__ whhT,
                                             const float* __restrict__ lbih,
                                             const float* __restrict__ lbhh,
                                             const float* __restrict__ fc1w,
                                             const float* __restrict__ fc1b,
                                             const float* __restrict__ fc2w,
                                             const float* __restrict__ fc2b,
                                             float* __restrict__ out) {
    __shared__ float sf[NPG * FP];
    __shared__ float sq[128];
    __shared__ float sh[64], scc[64];
    __shared__ float sg[256];
    __shared__ float se[NPG];
    __shared__ float red[2];
    int g = blockIdx.x, t = threadIdx.x;
    const float* fb = feat + (size_t)g * NPG * 64;
    for (int idx = t; idx < NPG * 64; idx += 256)
        sf[(idx >> 6) * FP + (idx & 63)] = fb[idx];
    if (t < 128) sq[t] = 0.f;
    if (t >= 128 && t < 192) { sh[t - 128] = 0.f; scc[t - 128] = 0.f; }
    __syncthreads();
    for (int it = 0; it < 3; it++) {
        float gate = lbih[t] + lbhh[t];
#pragma unroll 8
        for (int i = 0; i < 128; i++) gate += sq[i] * wihT[i * 256 + t];
#pragma unroll 8
        for (int i = 0; i < 64; i++) gate += sh[i] * whhT[i * 256 + t];
        sg[t] = gate;
        __syncthreads();
        if (t < 64) {
            float ig = sigmoidf_(sg[t]);
            float fg = sigmoidf_(sg[64 + t]);
            float gg = tanhf(sg[128 + t]);
            float og = sigmoidf_(sg[192 + t]);
            float c = fg * scc[t] + ig * gg;
            scc[t] = c;
            float hv = og * tanhf(c);
            sh[t] = hv;
            sq[t] = hv;
        }
        __syncthreads();
        if (t < NPG) {
            float e = 0.f;
#pragma unroll 8
            for (int o = 0; o < 64; o++) e += sf[t * FP + o] * sh[o];
            se[t] = e;
        }
        __syncthreads();
        if (t < 64) {
            float m = -1e30f;
            for (int i2 = t; i2 < NPG; i2 += 64) m = fmaxf(m, se[i2]);
            for (int d = 32; d; d >>= 1) m = fmaxf(m, __shfl_down(m, d));
            if (t == 0) red[0] = m;
        }
        __syncthreads();
        float emax = red[0];
        if (t < NPG) se[t] = __expf(se[t] - emax);
        __syncthreads();
        if (t < 64) {
            float s = 0.f;
            for (int i2 = t; i2 < NPG; i2 += 64) s += se[i2];
            for (int d = 32; d; d >>= 1) s += __shfl_down(s, d);
            if (t == 0) red[1] = s;
        }
        __syncthreads();
        if (t < 64) {
            float dnv = 1.f / red[1];
            float r = 0.f;
#pragma unroll 4
            for (int n = 0; n < NPG; n++) r += se[n] * sf[n * FP + t];
            sq[64 + t] = r * dnv;
        }
        __syncthreads();
    }
    if (t < 64) {
        float hsum = fc1b[t];
#pragma unroll 8
        for (int i = 0; i < 128; i++) hsum += sq[i] * fc1w[i * 64 + t];
        float p = fmaxf(hsum, 0.f) * fc2w[t];
        for (int d = 32; d; d >>= 1) p += __shfl_down(p, d);
        if (t == 0) out[g] = p + fc2b[0];
    }
}

extern "C" void kernel_launch(void* const* d_in, const int* in_sizes, int n_in,
                              void* d_out, int out_size, void* d_ws, size_t ws_size,
                              hipStream_t stream) {
    const float* nfeat = (const float*)d_in[0];
    const float* efeat = (const float*)d_in[1];
    const float* lin0_w = (const float*)d_in[2];
    const float* lin0_b = (const float*)d_in[3];
    const float* ew1 = (const float*)d_in[4];
    const float* eb1 = (const float*)d_in[5];
    const float* ew2 = (const float*)d_in[6];
    const float* eb2 = (const float*)d_in[7];
    const float* convb = (const float*)d_in[8];
    const float* gwih = (const float*)d_in[9];
    const float* gwhh = (const float*)d_in[10];
    const float* gbih = (const float*)d_in[11];
    const float* gbhh = (const float*)d_in[12];
    const float* lwih = (const float*)d_in[13];
    const float* lwhh = (const float*)d_in[14];
    const float* lbih = (const float*)d_in[15];
    const float* lbhh = (const float*)d_in[16];
    const float* fc1w = (const float*)d_in[17];
    const float* fc1b = (const float*)d_in[18];
    const float* fc2w = (const float*)d_in[19];
    const float* fc2b = (const float*)d_in[20];
    const int* src = (const int*)d_in[21];
    const int* dst = (const int*)d_in[22];
    float* out = (float*)d_out;

    char* p = (char*)d_ws;
    auto alloc = [&](size_t bytes) {
        char* q = p;
        p += (bytes + 255) & ~(size_t)255;
        return q;
    };
    f16x2* uP = (f16x2*)alloc((size_t)NUPL * EPAD * 4);     // 26.1 MB
    f16* w2hp = (f16*)alloc((size_t)NCH * 8192 * 2);        // 1.08 MB
    float* h = (float*)alloc((size_t)NNODE * 64 * 4);       // 12.8 MB
    float* agg = (float*)alloc((size_t)NNODE * 64 * 4);     // 12.8 MB
    int* cnt = (int*)alloc((size_t)NNODE * 4);
    float* lwihT = (float*)alloc((size_t)128 * 256 * 4);
    float* lwhhT = (float*)alloc((size_t)64 * 256 * 4);
    f16* gB1 = (f16*)alloc((size_t)12288 * 2);
    f16* gB2 = (f16*)alloc((size_t)12288 * 2);
    int* srcP = (int*)alloc((size_t)EPAD * 4);
    int* dstP = (int*)alloc((size_t)EPAD * 4);
    if ((size_t)(p - (char*)d_ws) > ws_size) return;  // ~55 MB total

    hipMemsetAsync(cnt, 0, (size_t)NNODE * 4, stream);
    hipMemsetAsync(agg, 0, (size_t)NNODE * 64 * 4, stream);  // once; k_gru2 re-zeroes

    k_prep_all<<<G_ALL, 256, 0, stream>>>(nfeat, lin0_w, lin0_b, efeat, ew1, eb1, ew2, eb2,
                                          gwih, gwhh, lwih, lwhh, src, dst,
                                          h, uP, w2hp, gB1, gB2, lwihT, lwhhT, srcP, dstP, cnt);

    for (int it = 0; it < 3; it++) {
        k_msg<<<EPAD / 256, 256, 0, stream>>>(h, uP, w2hp, srcP, dstP, agg);
        k_gru2<<<(NNODE + 63) / 64, 256, 0, stream>>>(agg, cnt, convb, gB1, gB2, gbih, gbhh, h,
                                                      it < 2 ? 1 : 0);
    }
    k_s2s<<<NGR, 256, 0, stream>>>(h, lwihT, lwhhT, lbih, lbhh, fc1w, fc1b, fc2w, fc2b, out);
}

// Round 17
// 466.380 us; speedup vs baseline: 1.1151x; 1.0821x over previous
//
#include <hip/hip_runtime.h>

#define HD 64
#define NNODE 50000
#define NEDGE 100000
#define NGR 500
#define NPG 100      // nodes per graph (sorted, contiguous, equal size)
#define EPAD 100352  // 392 * 256
#define NCH 66       // packed B chunks of K=128 (0..63 data, 64 = bias rows, 65 zero)
#define NUPL 65      // u planes: 64 data + 1 bias(=1)

typedef _Float16 f16;
typedef _Float16 f16x2 __attribute__((ext_vector_type(2)));
typedef _Float16 f16x8 __attribute__((ext_vector_type(8)));
typedef float f32x4 __attribute__((ext_vector_type(4)));

__device__ __forceinline__ float sigmoidf_(float x) { return 1.f / (1.f + __expf(-x)); }

__device__ __forceinline__ void gload16(const void* g, void* l) {
    __builtin_amdgcn_global_load_lds((const __attribute__((address_space(1))) unsigned int*)g,
                                     (__attribute__((address_space(3))) unsigned int*)l, 16, 0, 0);
}

// ================= fused prep kernel (incl. pack_b; node_init also zeroes agg) ==========
#define G_NODE 12500   // node_init: NNODE*64/256
#define G_EMLP 392     // edge_mlp: EPAD/256
#define G_PACK 66      // pack W2ext chunks
#define G_GRU  48      // prep_gru2
#define G_T1   128     // lwih transpose 256x128
#define G_T2   64      // lwhh transpose 256x64
#define G_IDX  392     // src/dst pad + degree count
#define G_ALL (G_NODE + G_EMLP + G_PACK + G_GRU + G_T1 + G_T2 + G_IDX)

__global__ __launch_bounds__(256) void k_prep_all(
    const float* __restrict__ nfeat, const float* __restrict__ lin0_w, const float* __restrict__ lin0_b,
    const float* __restrict__ efeat, const float* __restrict__ ew1, const float* __restrict__ eb1,
    const float* __restrict__ ew2, const float* __restrict__ eb2,
    const float* __restrict__ gwih, const float* __restrict__ gwhh,
    const float* __restrict__ lwih, const float* __restrict__ lwhh,
    const int* __restrict__ src, const int* __restrict__ dst,
    float* __restrict__ h, f16x2* __restrict__ uP, f16* __restrict__ w2hp,
    f16* __restrict__ gB1, f16* __restrict__ gB2,
    float* __restrict__ lwihT, float* __restrict__ lwhhT,
    int* __restrict__ srcP, int* __restrict__ dstP, int* __restrict__ cnt,
    float* __restrict__ agg) {
    __shared__ float sw[5 * 128];
    __shared__ float sb[128];
    __shared__ float s[8192];
    int bb = blockIdx.x;
    int t = threadIdx.x;
    if (bb < G_NODE) {  // ---- node_init (+ agg zero) ----
        int idx = bb * 256 + t;
        int n = idx >> 6, o = idx & 63;
        if (n >= NNODE) return;
        const float* nf = nfeat + n * 32;
        float acc = lin0_b[o];
#pragma unroll
        for (int i = 0; i < 32; i++) acc += nf[i] * lin0_w[i * 64 + o];
        h[idx] = fmaxf(acc, 0.f);
        agg[idx] = 0.f;
        return;
    }
    bb -= G_NODE;
    if (bb < G_EMLP) {  // ---- edge_mlp: uP[c][e] = (u[2c], u[2c+1]); plane 64 = bias(=1) ----
        for (int idx = t; idx < 640; idx += 256) sw[idx] = ew1[idx];
        if (t < 128) sb[t] = eb1[t];
        __syncthreads();
        int e = bb * 256 + t;
        bool valid = e < NEDGE;
        float ef[5];
#pragma unroll
        for (int i = 0; i < 5; i++) ef[i] = valid ? efeat[e * 5 + i] : 0.f;
#pragma unroll 2
        for (int c = 0; c < 64; c++) {
            float v[2];
#pragma unroll
            for (int ss = 0; ss < 2; ss++) {
                int k = 2 * c + ss;
                float acc = sb[k];
#pragma unroll
                for (int i = 0; i < 5; i++) acc += ef[i] * sw[i * 128 + k];
                v[ss] = valid ? fmaxf(acc, 0.f) : 0.f;
            }
            f16x2 pv;
            pv[0] = (f16)v[0];
            pv[1] = (f16)v[1];
            uP[(size_t)c * EPAD + e] = pv;
        }
        {   // bias plane: u == 1 (0 for padding edges)
            f16x2 pv;
            pv[0] = valid ? (f16)1.f : (f16)0.f;
            pv[1] = pv[0];
            uP[(size_t)64 * EPAD + e] = pv;
        }
        return;
    }
    bb -= G_EMLP;
    if (bb < G_PACK) {  // ---- pack W2ext chunk bb into MFMA B-frag order (LDS tiled) ----
        int c = bb;
        for (int i = t; i < 8192; i += 256) {
            int kg = c * 128 + (i >> 6);
            float v = 0.f;
            if (kg < 8192) v = ew2[(size_t)c * 8192 + i];
            else if (kg < 8256) v = eb2[(kg - 8192) * 64 + (i & 63)];
            s[i] = v;
        }
        __syncthreads();
        f16* outp = w2hp + (size_t)c * 8192 + t * 32;
#pragma unroll
        for (int ff = 0; ff < 4; ff++) {
            int F = t * 4 + ff;          // F = sl*256 + jj*64 + l
            int l = F & 63;
            int jj = (F >> 6) & 3;
            int sl = (F >> 8) & 3;
            f16x8 v;
#pragma unroll
            for (int q = 0; q < 8; q++)
                v[q] = (f16)s[(sl * 32 + ((l >> 4) << 3) + q) * 64 + jj * 16 + (l & 15)];
            *(f16x8*)(outp + ff * 8) = v;
        }
        return;
    }
    bb -= G_PACK;
    if (bb < G_GRU) {  // ---- GRU weights -> f16, gate-col permuted ----
        int idx = bb * 256 + t;
        int cp = idx >> 6, k = idx & 63;
        int w = cp / 48, rem = cp % 48;
        int tg = rem >> 4, cc = rem & 15;
        int orow = tg * 64 + w * 16 + cc;
        gB1[idx] = (f16)gwih[orow * 64 + k];
        gB2[idx] = (f16)gwhh[orow * 64 + k];
        return;
    }
    bb -= G_GRU;
    if (bb < G_T1) {  // ---- lwih transpose ----
        int idx = bb * 256 + t;
        int r = idx >> 7, c = idx & 127;
        lwihT[c * 256 + r] = lwih[idx];
        return;
    }
    bb -= G_T1;
    if (bb < G_T2) {  // ---- lwhh transpose ----
        int idx = bb * 256 + t;
        int r = idx >> 6, c = idx & 63;
        lwhhT[c * 256 + r] = lwhh[idx];
        return;
    }
    bb -= G_T2;
    {  // ---- src/dst pad + degree count ----
        int e = bb * 256 + t;
        if (e >= EPAD) return;
        if (e < NEDGE) {
            int d = dst[e];
            srcP[e] = src[e];
            dstP[e] = d;
            atomicAdd(&cnt[d], 1);
        } else {
            srcP[e] = 0;
            dstP[e] = -1;
        }
    }
}

// ---------------- K6: msg GEMM + atomic scatter, 4-wave LDS-staged B, BK=256 ----------
// Block = 4 waves x 64 edges = 256 edges, 64 cols (M_rep=4, N_rep=4, 16x16x32).
// TWO chunks (32KB) staged per barrier period, double-buffered (64KB LDS).
__global__ __launch_bounds__(256) void k_msg(
    const float* __restrict__ h, const f16x2* __restrict__ uP, const f16* __restrict__ w2hp,
    const int* __restrict__ srcP, const int* __restrict__ dstP, float* __restrict__ agg) {
    __shared__ __attribute__((aligned(16))) f16 sB[2 * 16384];  // 2 bufs x 32KB (2 chunks)
    int t = threadIdx.x;
    int w = t >> 6, l = t & 63;
    int eb = blockIdx.x * 256 + w * 64;  // per-wave edge base
    int lr = l & 15, lg = l >> 4;
    // A-side x fragments: xf[i][p][q] = f16(h[src[eb+i*16+lr]][p*32 + lg*8 + q])
    f16x8 xf[4][2];
#pragma unroll
    for (int i = 0; i < 4; i++) {
        const float* xb = h + (size_t)srcP[eb + i * 16 + lr] * 64;
#pragma unroll
        for (int p = 0; p < 2; p++) {
            float4 v0 = *(const float4*)(xb + p * 32 + lg * 8);
            float4 v1 = *(const float4*)(xb + p * 32 + lg * 8 + 4);
            f16x8 xv;
            xv[0] = (f16)v0.x; xv[1] = (f16)v0.y; xv[2] = (f16)v0.z; xv[3] = (f16)v0.w;
            xv[4] = (f16)v1.x; xv[5] = (f16)v1.y; xv[6] = (f16)v1.z; xv[7] = (f16)v1.w;
            xf[i][p] = xv;
        }
    }
    const f16x8* gB = (const f16x8*)w2hp;
    f16x8* sB8 = (f16x8*)sB;
    // stage pair 0 (chunks 0,1) into buf 0: 8 f16x8 slots per thread
#pragma unroll
    for (int i = 0; i < 8; i++)
        gload16(gB + i * 256 + t, sB8 + i * 256 + t);
    f32x4 acc[4][4];
#pragma unroll
    for (int i = 0; i < 4; i++)
#pragma unroll
        for (int j = 0; j < 4; j++) acc[i][j] = (f32x4){0.f, 0.f, 0.f, 0.f};
    f16x2 uc0[4], uc1[4], un0[4], un1[4];
#pragma unroll
    for (int i = 0; i < 4; i++) {
        uc0[i] = uP[eb + i * 16 + lr];                  // plane 0
        uc1[i] = uP[(size_t)EPAD + eb + i * 16 + lr];   // plane 1
    }
    __syncthreads();  // drains vmcnt: buf0 ready
#pragma unroll 1
    for (int p = 0; p <= 32; p++) {
        int buf = p & 1;
        if (p < 32) {  // stage next pair into other buffer + prefetch u planes
            const f16x8* gs = gB + (size_t)(p + 1) * 2048;
            f16x8* ld = sB8 + (buf ^ 1) * 2048;
#pragma unroll
            for (int i = 0; i < 8; i++)
                gload16(gs + i * 256 + t, ld + i * 256 + t);
            int c0 = min(2 * p + 2, 64), c1 = min(2 * p + 3, 64);
#pragma unroll
            for (int i = 0; i < 4; i++) {
                un0[i] = uP[(size_t)c0 * EPAD + eb + i * 16 + lr];
                un1[i] = uP[(size_t)c1 * EPAD + eb + i * 16 + lr];
            }
        }
        {   // chunk 2p (first half of buffer)
            f16x8 bf[4][4];
#pragma unroll
            for (int s = 0; s < 4; s++)
#pragma unroll
                for (int j = 0; j < 4; j++)
                    bf[s][j] = sB8[buf * 2048 + s * 256 + j * 64 + l];
            __builtin_amdgcn_s_setprio(1);
#pragma unroll
            for (int s = 0; s < 4; s++)
#pragma unroll
                for (int i = 0; i < 4; i++) {
                    f16x8 av = xf[i][s & 1] * uc0[i][s >> 1];
#pragma unroll
                    for (int j = 0; j < 4; j++)
                        acc[i][j] = __builtin_amdgcn_mfma_f32_16x16x32_f16(av, bf[s][j], acc[i][j], 0, 0, 0);
                }
            __builtin_amdgcn_s_setprio(0);
        }
        {   // chunk 2p+1 (second half of buffer)
            f16x8 bf[4][4];
#pragma unroll
            for (int s = 0; s < 4; s++)
#pragma unroll
                for (int j = 0; j < 4; j++)
                    bf[s][j] = sB8[buf * 2048 + 1024 + s * 256 + j * 64 + l];
            __builtin_amdgcn_s_setprio(1);
#pragma unroll
            for (int s = 0; s < 4; s++)
#pragma unroll
                for (int i = 0; i < 4; i++) {
                    f16x8 av = xf[i][s & 1] * uc1[i][s >> 1];
#pragma unroll
                    for (int j = 0; j < 4; j++)
                        acc[i][j] = __builtin_amdgcn_mfma_f32_16x16x32_f16(av, bf[s][j], acc[i][j], 0, 0, 0);
                }
            __builtin_amdgcn_s_setprio(0);
        }
#pragma unroll
        for (int i = 0; i < 4; i++) { uc0[i] = un0[i]; uc1[i] = un1[i]; }
        __syncthreads();  // all reads of buf done; staged buf^1 landed (vmcnt drained)
    }
    // atomic scatter: C layout col=lane&15, row=(lane>>4)*4+reg
#pragma unroll
    for (int i = 0; i < 4; i++) {
        int rb = eb + i * 16 + lg * 4;
        int4 d4 = *(const int4*)(dstP + rb);
#pragma unroll
        for (int r = 0; r < 4; r++) {
            int d = (r == 0) ? d4.x : (r == 1) ? d4.y : (r == 2) ? d4.z : d4.w;
            if (d >= 0) {
                float* ap = agg + (size_t)d * 64 + lr;
#pragma unroll
                for (int j = 0; j < 4; j++) atomicAdd(ap + j * 16, acc[i][j][r]);
            }
        }
    }
}

// ---------------- K7: GRU via MFMA, 64 nodes/block; optionally zeroes agg --------
#define GWP 72
__global__ __launch_bounds__(256) void k_gru2(float* __restrict__ agg,
                                              const int* __restrict__ cnt,
                                              const float* __restrict__ convb,
                                              const f16* __restrict__ B1g,
                                              const f16* __restrict__ B2g,
                                              const float* __restrict__ bih,
                                              const float* __restrict__ bhh,
                                              float* __restrict__ h, int zero_agg) {
    __shared__ f16 sM[64 * GWP];
    __shared__ f16 sH[64 * GWP];
    int t = threadIdx.x;
    int nb = blockIdx.x * 64;
    int w = t >> 6, l = t & 63, lr = l & 15, lg = l >> 4;
    f16x8 b1[2][3], b2[2][3];
#pragma unroll
    for (int kk = 0; kk < 2; kk++)
#pragma unroll
        for (int j = 0; j < 3; j++) {
            size_t off = (size_t)(w * 48 + j * 16 + lr) * 64 + kk * 32 + lg * 8;
            b1[kk][j] = *(const f16x8*)(B1g + off);
            b2[kk][j] = *(const f16x8*)(B2g + off);
        }
#pragma unroll
    for (int it = 0; it < 16; it++) {
        int idx = t + 256 * it;
        int node = idx >> 6, k = idx & 63;
        int gn = nb + node;
        float mv = 0.f, hv = 0.f;
        if (gn < NNODE) {
            size_t off = (size_t)gn * 64 + k;
            float dinv = 1.f / (float)max(cnt[gn], 1);
            mv = fmaxf(agg[off] * dinv + convb[k], 0.f);
            hv = h[off];
            if (zero_agg) agg[off] = 0.f;  // reset for next msg pass
        }
        sM[node * GWP + k] = (f16)mv;
        sH[node * GWP + k] = (f16)hv;
    }
    __syncthreads();
    f32x4 aih[4][3], ahh[4][3];
#pragma unroll
    for (int i = 0; i < 4; i++)
#pragma unroll
        for (int j = 0; j < 3; j++) {
            aih[i][j] = (f32x4){0.f, 0.f, 0.f, 0.f};
            ahh[i][j] = (f32x4){0.f, 0.f, 0.f, 0.f};
        }
#pragma unroll
    for (int kk = 0; kk < 2; kk++) {
        f16x8 am[4], ah[4];
#pragma unroll
        for (int i = 0; i < 4; i++) {
            am[i] = *(const f16x8*)(sM + (i * 16 + lr) * GWP + kk * 32 + lg * 8);
            ah[i] = *(const f16x8*)(sH + (i * 16 + lr) * GWP + kk * 32 + lg * 8);
        }
#pragma unroll
        for (int i = 0; i < 4; i++)
#pragma unroll
            for (int j = 0; j < 3; j++) {
                aih[i][j] = __builtin_amdgcn_mfma_f32_16x16x32_f16(am[i], b1[kk][j], aih[i][j], 0, 0, 0);
                ahh[i][j] = __builtin_amdgcn_mfma_f32_16x16x32_f16(ah[i], b2[kk][j], ahh[i][j], 0, 0, 0);
            }
    }
    float bi0 = bih[0 * 64 + w * 16 + lr], bh0 = bhh[0 * 64 + w * 16 + lr];
    float bi1 = bih[1 * 64 + w * 16 + lr], bh1 = bhh[1 * 64 + w * 16 + lr];
    float bi2 = bih[2 * 64 + w * 16 + lr], bh2 = bhh[2 * 64 + w * 16 + lr];
#pragma unroll
    for (int i = 0; i < 4; i++)
#pragma unroll
        for (int r = 0; r < 4; r++) {
            int node = i * 16 + lg * 4 + r;
            int gn = nb + node;
            if (gn >= NNODE) continue;
            float rg = sigmoidf_(aih[i][0][r] + bi0 + ahh[i][0][r] + bh0);
            float z = sigmoidf_(aih[i][1][r] + bi1 + ahh[i][1][r] + bh1);
            float nn = tanhf(aih[i][2][r] + bi2 + rg * (ahh[i][2][r] + bh2));
            size_t off = (size_t)gn * 64 + w * 16 + lr;
            float hold = h[off];
            h[off] = (1.f - z) * nn + z * hold;
        }
}

// ---------------- K8: fused Set2Set (3x LSTM + attention) + final MLP, block per graph ----
#define FP 68
__global__ __launch_bounds__(256) void k_s2s(const float* __restrict__ feat,
                                             const float* __restrict__ wihT,
                                             const float* __restrict__ whhT,
                                             const float* __restrict__ lbih,
                                             const float* __restrict__ lbhh,
                                             const float* __restrict__ fc1w,
                                             const float* __restrict__ fc1b,
                                             const float* __restrict__ fc2w,
                                             const float* __restrict__ fc2b,
                                             float* __restrict__ out) {
    __shared__ float sf[NPG * FP];
    __shared__ float sq[128];
    __shared__ float sh[64], scc[64];
    __shared__ float sg[256];
    __shared__ float se[NPG];
    __shared__ float red[2];
    int g = blockIdx.x, t = threadIdx.x;
    const float* fb = feat + (size_t)g * NPG * 64;
    for (int idx = t; idx < NPG * 64; idx += 256)
        sf[(idx >> 6) * FP + (idx & 63)] = fb[idx];
    if (t < 128) sq[t] = 0.f;
    if (t >= 128 && t < 192) { sh[t - 128] = 0.f; scc[t - 128] = 0.f; }
    __syncthreads();
    for (int it = 0; it < 3; it++) {
        float gate = lbih[t] + lbhh[t];
#pragma unroll 8
        for (int i = 0; i < 128; i++) gate += sq[i] * wihT[i * 256 + t];
#pragma unroll 8
        for (int i = 0; i < 64; i++) gate += sh[i] * whhT[i * 256 + t];
        sg[t] = gate;
        __syncthreads();
        if (t < 64) {
            float ig = sigmoidf_(sg[t]);
            float fg = sigmoidf_(sg[64 + t]);
            float gg = tanhf(sg[128 + t]);
            float og = sigmoidf_(sg[192 + t]);
            float c = fg * scc[t] + ig * gg;
            scc[t] = c;
            float hv = og * tanhf(c);
            sh[t] = hv;
            sq[t] = hv;
        }
        __syncthreads();
        if (t < NPG) {
            float e = 0.f;
#pragma unroll 8
            for (int o = 0; o < 64; o++) e += sf[t * FP + o] * sh[o];
            se[t] = e;
        }
        __syncthreads();
        if (t < 64) {
            float m = -1e30f;
            for (int i2 = t; i2 < NPG; i2 += 64) m = fmaxf(m, se[i2]);
            for (int d = 32; d; d >>= 1) m = fmaxf(m, __shfl_down(m, d));
            if (t == 0) red[0] = m;
        }
        __syncthreads();
        float emax = red[0];
        if (t < NPG) se[t] = __expf(se[t] - emax);
        __syncthreads();
        if (t < 64) {
            float s = 0.f;
            for (int i2 = t; i2 < NPG; i2 += 64) s += se[i2];
            for (int d = 32; d; d >>= 1) s += __shfl_down(s, d);
            if (t == 0) red[1] = s;
        }
        __syncthreads();
        if (t < 64) {
            float dnv = 1.f / red[1];
            float r = 0.f;
#pragma unroll 4
            for (int n = 0; n < NPG; n++) r += se[n] * sf[n * FP + t];
            sq[64 + t] = r * dnv;
        }
        __syncthreads();
    }
    if (t < 64) {
        float hsum = fc1b[t];
#pragma unroll 8
        for (int i = 0; i < 128; i++) hsum += sq[i] * fc1w[i * 64 + t];
        float p = fmaxf(hsum, 0.f) * fc2w[t];
        for (int d = 32; d; d >>= 1) p += __shfl_down(p, d);
        if (t == 0) out[g] = p + fc2b[0];
    }
}

extern "C" void kernel_launch(void* const* d_in, const int* in_sizes, int n_in,
                              void* d_out, int out_size, void* d_ws, size_t ws_size,
                              hipStream_t stream) {
    const float* nfeat = (const float*)d_in[0];
    const float* efeat = (const float*)d_in[1];
    const float* lin0_w = (const float*)d_in[2];
    const float* lin0_b = (const float*)d_in[3];
    const float* ew1 = (const float*)d_in[4];
    const float* eb1 = (const float*)d_in[5];
    const float* ew2 = (const float*)d_in[6];
    const float* eb2 = (const float*)d_in[7];
    const float* convb = (const float*)d_in[8];
    const float* gwih = (const float*)d_in[9];
    const float* gwhh = (const float*)d_in[10];
    const float* gbih = (const float*)d_in[11];
    const float* gbhh = (const float*)d_in[12];
    const float* lwih = (const float*)d_in[13];
    const float* lwhh = (const float*)d_in[14];
    const float* lbih = (const float*)d_in[15];
    const float* lbhh = (const float*)d_in[16];
    const float* fc1w = (const float*)d_in[17];
    const float* fc1b = (const float*)d_in[18];
    const float* fc2w = (const float*)d_in[19];
    const float* fc2b = (const float*)d_in[20];
    const int* src = (const int*)d_in[21];
    const int* dst = (const int*)d_in[22];
    float* out = (float*)d_out;

    char* p = (char*)d_ws;
    auto alloc = [&](size_t bytes) {
        char* q = p;
        p += (bytes + 255) & ~(size_t)255;
        return q;
    };
    f16x2* uP = (f16x2*)alloc((size_t)NUPL * EPAD * 4);     // 26.1 MB
    f16* w2hp = (f16*)alloc((size_t)NCH * 8192 * 2);        // 1.08 MB
    float* h = (float*)alloc((size_t)NNODE * 64 * 4);       // 12.8 MB
    float* agg = (float*)alloc((size_t)NNODE * 64 * 4);     // 12.8 MB
    int* cnt = (int*)alloc((size_t)NNODE * 4);
    float* lwihT = (float*)alloc((size_t)128 * 256 * 4);
    float* lwhhT = (float*)alloc((size_t)64 * 256 * 4);
    f16* gB1 = (f16*)alloc((size_t)12288 * 2);
    f16* gB2 = (f16*)alloc((size_t)12288 * 2);
    int* srcP = (int*)alloc((size_t)EPAD * 4);
    int* dstP = (int*)alloc((size_t)EPAD * 4);
    if ((size_t)(p - (char*)d_ws) > ws_size) return;  // ~55 MB total

    hipMemsetAsync(cnt, 0, (size_t)NNODE * 4, stream);

    k_prep_all<<<G_ALL, 256, 0, stream>>>(nfeat, lin0_w, lin0_b, efeat, ew1, eb1, ew2, eb2,
                                          gwih, gwhh, lwih, lwhh, src, dst,
                                          h, uP, w2hp, gB1, gB2, lwihT, lwhhT, srcP, dstP, cnt,
                                          agg);

    for (int it = 0; it < 3; it++) {
        k_msg<<<EPAD / 256, 256, 0, stream>>>(h, uP, w2hp, srcP, dstP, agg);
        k_gru2<<<(NNODE + 63) / 64, 256, 0, stream>>>(agg, cnt, convb, gB1, gB2, gbih, gbhh, h,
                                                      it < 2 ? 1 : 0);
    }
    k_s2s<<<NGR, 256, 0, stream>>>(h, lwihT, lwhhT, lbih, lbhh, fc1w, fc1b, fc2w, fc2b, out);
}